// Round 6
// baseline (118.284 us; speedup 1.0000x reference)
//
#include <hip/hip_runtime.h>
#include <hip/hip_bf16.h>
#include <stdint.h>

#define CIN   512
#define COUT  512
#define BM    128
#define BN    128
#define NIB   16            // 512/32 i-blocks
#define KSTEPS 128          // NIB * 8 degrees (d=1..8); d=0 folded into bias

typedef float f32x16 __attribute__((ext_vector_type(16)));
typedef short s16x8 __attribute__((ext_vector_type(8)));

// Frag-packed bf16 weights for mfma_32x32x16: [ks(128)][kh(2)][cg32(16)][lane(64)]
// lane l holds B[k = 8*(l>>5)+j][col = l&31], j=0..7; i = ib*32 + kh*16 + k.
__device__ uint4 Wp_g[KSTEPS * 2 * 16 * 64];   // 4 MB
__device__ float bias_g[COUT];

__device__ __forceinline__ uint32_t cvtpk(float lo, float hi) {
  uint32_t r;
  asm("v_cvt_pk_bf16_f32 %0, %1, %2" : "=v"(r) : "v"(lo), "v"(hi));
  return r;  // low 16 = bf16(lo), high 16 = bf16(hi)
}

__device__ __forceinline__ float ftanh(float v) {
  float e = __expf(v + v);
  return 1.0f - __fdividef(2.0f, e + 1.0f);
}

// ---- pack weights into 32x32x16 MFMA B-fragment order (coalesced via LDS) ----
__global__ void pack_w(const float* __restrict__ cw) {
  __shared__ float lf[32 * 288];   // 32 i x (32 o x 9 d)
  int ib = blockIdx.x >> 4;
  int cg = blockIdx.x & 15;
  for (int r = threadIdx.x; r < 32 * 288; r += 256) {
    int il = r / 288;
    int rem = r - il * 288;
    lf[r] = cw[(size_t)(ib * 32 + il) * (COUT * 9) + cg * 288 + rem];
  }
  __syncthreads();
  for (int v = threadIdx.x; v < 1024; v += 256) {
    int lane = v & 63;
    int kh   = (v >> 6) & 1;
    int dm1  = v >> 7;            // 0..7
    int d    = dm1 + 1;
    int i0   = kh * 16 + (lane >> 5) * 8;
    int ol   = lane & 31;
    uint32_t p[4];
    #pragma unroll
    for (int q = 0; q < 4; ++q) {
      float a = lf[(i0 + 2 * q    ) * 288 + ol * 9 + d];
      float b = lf[(i0 + 2 * q + 1) * 288 + ol * 9 + d];
      p[q] = cvtpk(a, b);
    }
    Wp_g[(((ib * 8 + dm1) * 2 + kh) * 16 + cg) * 64 + lane] =
        make_uint4(p[0], p[1], p[2], p[3]);
  }
}

// ---- bias[o] = sum_i C[i][o][0] (d=0 / T_0==1 term): one block per o ----
__global__ void bias_k(const float* __restrict__ cw) {
  int o = blockIdx.x;
  int t = threadIdx.x;
  float s = 0.f;
  #pragma unroll
  for (int q = 0; q < 8; ++q)
    s += cw[(size_t)(t + 64 * q) * (COUT * 9) + o * 9];
  #pragma unroll
  for (int off = 32; off; off >>= 1) s += __shfl_down(s, off);
  if (t == 0) bias_g[o] = s;
}

// ---- fused basis-generation + GEMM, m201-style phase discipline ----
// 128x128 tile, 8 waves (2x4 grid of 64x32), 32x32x16 MFMA, grid=512
// (2 independent blocks/CU). A generated into half-double-buffered LDS
// (round-2 PART0/PART1). Per kstep: window (B prefetch + gen + A ds_read)
// -> lgkmcnt(0) -> s_barrier -> setprio(1) MFMA x4 setprio(0) -> s_barrier.
// Raw barriers never drain vmcnt: B prefetch spans barriers (T4).
__global__ void __launch_bounds__(512, 4) cheby_gemm(const float* __restrict__ x,
                                                     float* __restrict__ out) {
  __shared__ uint4 lds[2 * 4 * 4 * BM];   // [buf][slot(4 d)][h(4)][row(128)] = 64 KB
  const int tid  = threadIdx.x;
  const int lane = tid & 63;
  const int l31  = lane & 31;
  const int lh5  = lane >> 5;
  const int w    = tid >> 6;        // 0..7
  const int wr   = w >> 2;          // 2 row-groups of 64
  const int wc   = w & 3;           // 4 col-groups of 32

  // bijective XCD swizzle (512 blocks, 512 % 8 == 0)
  int b0  = blockIdx.x;
  int bid = (b0 & 7) * 64 + (b0 >> 3);
  const int rb   = (bid >> 2) * BM;
  const int cb   = bid & 3;
  const int ocb  = cb * BN;
  const int cg32 = cb * 4 + wc;     // 16 col-groups of 32 over COUT

  // generator mapping (all 8 waves): 8 chains/thread, contiguous uint4 emit
  const int ge   = w >> 1;                 // i-chunk of 8 (0..3)
  const int grow = (w & 1) * 64 + lane;    // row (0..127)
  const float* xrow = x + (size_t)(rb + grow) * CIN + ge * 8;

  // B pointer hoist: element [ks][kh] at offset (ks*2+kh)*1024
  const uint4* pB = Wp_g + (size_t)cg32 * 64 + lane;

  // accumulators (f32x16 per 32x32 block), init with d=0 bias term
  f32x16 acc[2];
  {
    float bv = bias_g[ocb + wc * 32 + l31];
    #pragma unroll
    for (int rf = 0; rf < 2; ++rf)
      #pragma unroll
      for (int r = 0; r < 16; ++r) acc[rf][r] = bv;
  }

  float xv[8], u2[8], tm1[8], tm2[8];

  auto loadX = [&](int ib) {
    const float4* p = reinterpret_cast<const float4*>(xrow + ib * 32);
    float4 v0 = p[0], v1 = p[1];
    xv[0] = v0.x; xv[1] = v0.y; xv[2] = v0.z; xv[3] = v0.w;
    xv[4] = v1.x; xv[5] = v1.y; xv[6] = v1.z; xv[7] = v1.w;
  };
  auto compute_u = [&]() {
    #pragma unroll
    for (int k = 0; k < 8; ++k) {
      float u = ftanh(ftanh(xv[k]));
      tm1[k] = u; tm2[k] = 1.0f; u2[k] = u + u;
    }
  };
  auto advance = [&]() {
    #pragma unroll
    for (int k = 0; k < 8; ++k) {
      float t = __builtin_fmaf(u2[k], tm1[k], -tm2[k]);
      tm2[k] = tm1[k]; tm1[k] = t;
    }
  };
  auto emit = [&](int buf, int slot) {   // write current tm1[] (= T_d) as bf16
    uint32_t p0 = cvtpk(tm1[0], tm1[1]);
    uint32_t p1 = cvtpk(tm1[2], tm1[3]);
    uint32_t p2 = cvtpk(tm1[4], tm1[5]);
    uint32_t p3 = cvtpk(tm1[6], tm1[7]);
    lds[((buf * 4 + slot) * 4 + ge) * BM + grow] = make_uint4(p0, p1, p2, p3);
  };

  s16x8 breg[2][2];                 // [parity][kh]
  auto loadB = [&](int par, int ks) {
    #pragma unroll
    for (int kh = 0; kh < 2; ++kh) {
      uint4 v = pB[(size_t)(ks * 2 + kh) * 1024];
      breg[par][kh] = __builtin_bit_cast(s16x8, v);
    }
  };

  // one phase: window tail (A ds_read) -> lgkm drain -> barrier -> MFMA -> barrier
  auto phase_mfma = [&](int buf, int slot, int par) {
    s16x8 a[2][2];
    #pragma unroll
    for (int rf = 0; rf < 2; ++rf)
      #pragma unroll
      for (int kh = 0; kh < 2; ++kh)
        a[rf][kh] = *reinterpret_cast<const s16x8*>(
            &lds[((buf * 4 + slot) * 4 + 2 * kh + lh5) * BM + wr * 64 + rf * 32 + l31]);
    asm volatile("s_waitcnt lgkmcnt(0)" ::: "memory");
    __builtin_amdgcn_sched_barrier(0);
    __builtin_amdgcn_s_barrier();
    __builtin_amdgcn_s_setprio(1);
    #pragma unroll
    for (int kh = 0; kh < 2; ++kh)
      #pragma unroll
      for (int rf = 0; rf < 2; ++rf)
        acc[rf] = __builtin_amdgcn_mfma_f32_32x32x16_bf16(
            a[rf][kh], breg[par][kh], acc[rf], 0, 0, 0);
    __builtin_amdgcn_s_setprio(0);
    __builtin_amdgcn_s_barrier();
  };

  // ---- prologue: generate (ib=0, d=1..4) into buf0 ----
  loadX(0);
  compute_u();
  emit(0, 0);                 // d=1 : T_1 = u
  advance(); emit(0, 1);      // d=2
  advance(); emit(0, 2);      // d=3
  advance(); emit(0, 3);      // d=4
  loadB(0, 0);
  asm volatile("s_waitcnt lgkmcnt(0)" ::: "memory");
  __builtin_amdgcn_sched_barrier(0);
  __builtin_amdgcn_s_barrier();

  for (int ib = 0; ib < NIB; ++ib) {
    // PART 0: consume buf0 (d=1..4); generate (ib, d=5..8) -> buf1
    #pragma unroll
    for (int j = 0; j < 4; ++j) {
      int ks = ib * 8 + j;
      loadB((j + 1) & 1, ks + 1);            // ks+1 <= 124 always here
      if (j == 0 && ib + 1 < NIB) loadX(ib + 1);   // for compute_u in PART1
      advance(); emit(1, j);                 // d = 5+j
      phase_mfma(0, j, j & 1);
    }
    // PART 1: consume buf1 (d=5..8); generate (ib+1, d=1..4) -> buf0
    #pragma unroll
    for (int j = 0; j < 4; ++j) {
      int ks = ib * 8 + 4 + j;
      if (ks + 1 < KSTEPS) loadB((j + 1) & 1, ks + 1);
      if (ib + 1 < NIB) {
        if (j == 0) { compute_u(); emit(0, 0); }
        else        { advance();   emit(0, j); }
      }
      phase_mfma(1, j, j & 1);
    }
  }

  // ---- epilogue: 32x32 C/D layout col=lane&31, row=(r&3)+8*(r>>2)+4*(lane>>5)
  const int ocol  = ocb + wc * 32 + l31;
  const int rbase = rb + wr * 64 + 4 * lh5;
  #pragma unroll
  for (int rf = 0; rf < 2; ++rf) {
    #pragma unroll
    for (int r = 0; r < 16; ++r) {
      int row = rbase + rf * 32 + (r & 3) + 8 * (r >> 2);
      out[(size_t)row * COUT + ocol] = acc[rf][r];
    }
  }
}

extern "C" void kernel_launch(void* const* d_in, const int* in_sizes, int n_in,
                              void* d_out, int out_size, void* d_ws, size_t ws_size,
                              hipStream_t stream) {
  const float* x  = (const float*)d_in[0];   // (16384, 512) fp32
  const float* cw = (const float*)d_in[1];   // (512, 512, 9) fp32
  float* out = (float*)d_out;                // (16384, 512) fp32

  pack_w<<<dim3(256), dim3(256), 0, stream>>>(cw);
  bias_k<<<dim3(COUT), dim3(64), 0, stream>>>(cw);
  cheby_gemm<<<dim3(512), dim3(512), 0, stream>>>(x, out);
}